// Round 2
// baseline (2084.891 us; speedup 1.0000x reference)
//
#include <hip/hip_runtime.h>
#include <cstddef>
#include <cstdint>

// ---------------------------------------------------------------------------
// LSTM layer: T=512, B=64, I=512, H=512.
// Phase 1: xW = x @ W + b  (bf16 MFMA GEMM), epilogue writes xWp in
//          per-WG-per-step contiguous layout [t][blk][slice][gate][256].
// Phase 2: persistent recurrence, 128 WGs = 4 batch-blocks x 32 hidden-slices.
//   R8:  tagged-word exchange with coalesced dwordx4 sc1 staging, bulk load
//        doubles as the freshness poll (data+check in one MALL round trip).
//   R10: span-granular retry. Each (wave,chunk) span of the bulk load covers
//        exactly ONE producer slice (slice j = 4*chunk + wave), so validation
//        is per-wave __all(min4(d) >= tag) with no cross-wave sync, and
//        retries re-load only the stale 1KB spans instead of all 32KB.
//        (R9's flag pre-gate regressed: it serialized detect->fetch into two
//        round trips and hot-spotted 2 cache lines; reverted.)
// ---------------------------------------------------------------------------

#define T_STEPS 512
#define NB      64      // batch
#define HID     512
#define G4      2048    // 4*H
#define KDIM    512
#define BB      4       // batch blocks (16 rows each)
#define NSL     32      // hidden slices (16 units each)
#define BLK_DW  (NSL * 256)          // dwords per (parity,block) region = 8192
#define PAR_DW  (BB * BLK_DW)        // dwords per parity = 32768

typedef short bf16x8 __attribute__((ext_vector_type(8)));
typedef float f32x4  __attribute__((ext_vector_type(4)));
typedef unsigned int u32x4 __attribute__((ext_vector_type(4)));

__device__ __forceinline__ float bf2f(unsigned short s) {
    unsigned u = ((unsigned)s) << 16;
    float f; __builtin_memcpy(&f, &u, 4); return f;
}
__device__ __forceinline__ unsigned short f2bf(float f) {
    unsigned u; __builtin_memcpy(&u, &f, 4);
    u = (u + 0x7FFFu + ((u >> 16) & 1u)) >> 16;
    return (unsigned short)u;
}
__device__ __forceinline__ unsigned min4(u32x4 v) {
    unsigned a = v[0] < v[1] ? v[0] : v[1];
    unsigned b = v[2] < v[3] ? v[2] : v[3];
    return a < b ? a : b;
}

// ---------------- kernel 1: cast x to bf16 + zero both abq parity regions --
__global__ void cast_x_kernel(const float* __restrict__ x,
                              unsigned short* __restrict__ o,
                              unsigned* __restrict__ abq) {
    if (blockIdx.x < 256)   // 256 x 256 = 65536 dwords = 256 KB
        abq[blockIdx.x * 256 + threadIdx.x] = 0u;   // tag 0 = stale
    size_t i = (size_t)blockIdx.x * blockDim.x + threadIdx.x;  // one float4 each
    float4 v = ((const float4*)x)[i];
    ushort4 r;
    r.x = f2bf(v.x); r.y = f2bf(v.y); r.z = f2bf(v.z); r.w = f2bf(v.w);
    ((ushort4*)o)[i] = r;
}

// ---------------- kernel 2: transpose+cast [512][2048] f32 -> [2048][512] bf16
__global__ void transpose_cast(const float* __restrict__ src,
                               unsigned short* __restrict__ dst) {
    __shared__ float tile[64][65];
    const int n0 = blockIdx.x * 64;
    const int k0 = blockIdx.y * 64;
    const int c  = threadIdx.x & 63;
    const int r0 = threadIdx.x >> 6;
    for (int p = 0; p < 16; ++p) {
        int r = p * 4 + r0;
        tile[r][c] = src[(size_t)(k0 + r) * G4 + n0 + c];
    }
    __syncthreads();
    for (int p = 0; p < 16; ++p) {
        int r = p * 4 + r0;
        dst[(size_t)(n0 + r) * KDIM + k0 + c] = f2bf(tile[c][r]);
    }
}

// ---------------- kernel 3: bf16 MFMA GEMM, recurrence-layout epilogue ------
// C layout: [t][blk][slice][gate][bt*16+ut] bf16 (contiguous 2 KB per WG-step)
__global__ __launch_bounds__(256) void gemm_xw(
        const unsigned short* __restrict__ A,
        const unsigned short* __restrict__ Bt,
        const float* __restrict__ bias,
        unsigned short* __restrict__ C) {
    __shared__ unsigned short As[128][56];
    __shared__ unsigned short Bs[128][56];
    const int m0 = blockIdx.x * 128;
    const int n0 = blockIdx.y * 128;
    const int tid = threadIdx.x;
    const int lane = tid & 63, wave = tid >> 6;
    const int quad = lane >> 4, l16 = lane & 15;
    const int wm = (wave >> 1) * 64, wn = (wave & 1) * 64;
    f32x4 acc[4][4];
    for (int i = 0; i < 4; ++i)
        for (int j = 0; j < 4; ++j) acc[i][j] = (f32x4)0.0f;
    const int srow = tid >> 2, scol = (tid & 3) * 8;
    for (int k0 = 0; k0 < KDIM; k0 += 32) {
        __syncthreads();
        for (int p = 0; p < 2; ++p) {
            int row = p * 64 + srow;
            *(uint4*)&As[row][scol] =
                *(const uint4*)&A[(size_t)(m0 + row) * KDIM + k0 + scol];
            *(uint4*)&Bs[row][scol] =
                *(const uint4*)&Bt[(size_t)(n0 + row) * KDIM + k0 + scol];
        }
        __syncthreads();
        bf16x8 af[4], bf[4];
        for (int i = 0; i < 4; ++i)
            af[i] = *(const bf16x8*)&As[wm + i * 16 + l16][quad * 8];
        for (int j = 0; j < 4; ++j)
            bf[j] = *(const bf16x8*)&Bs[wn + j * 16 + l16][quad * 8];
        for (int i = 0; i < 4; ++i)
            for (int j = 0; j < 4; ++j)
                acc[i][j] = __builtin_amdgcn_mfma_f32_16x16x32_bf16(
                    af[i], bf[j], acc[i][j], 0, 0, 0);
    }
    for (int i = 0; i < 4; ++i)
        for (int j = 0; j < 4; ++j) {
            int col = n0 + wn + j * 16 + l16;          // 0..2047
            int g   = col >> 9;                        // gate
            int u   = col & 511;                       // hidden unit
            int js  = u >> 4, ut = u & 15;
            float bv = bias[col];
            for (int r = 0; r < 4; ++r) {
                int row = m0 + wm + i * 16 + quad * 4 + r;   // t*64 + b
                int t = row >> 6, b = row & 63;
                size_t off = ((((size_t)t * BB + (b >> 4)) * NSL + js) * 4 + g)
                                 * 256 + (b & 15) * 16 + ut;
                C[off] = f2bf(acc[i][j][r] + bv);
            }
        }
}

// ---------------- kernel 4: persistent recurrence (tagged, span retry) -----
// abq dword layout: [parity][block i][slice j][d], d = b_local*16 + u_local.
// Word = bf16(value) | version<<16. Version of a_t is t+1 (a0 -> 1).
__global__ __launch_bounds__(256) void lstm_rec(
        const unsigned short* __restrict__ xWp,  // [t][blk][slice][4][256] bf16
        const unsigned short* __restrict__ Ut,   // [2048][512] bf16
        const float* __restrict__ a0,            // [64][512] f32
        float* __restrict__ out,                 // [T*64][512] f32
        unsigned* __restrict__ abq) {            // 2*4*32*256 dwords = 256 KB
    __shared__ unsigned short a_lds[16][520];    // [batch-local][k-global]
    __shared__ float gbuf[4][16][20];            // [gate][batch-local][unit]
    const int wgid  = blockIdx.x;
    const int i_blk = wgid >> 5;                 // batch block 0..3
    const int j_sl  = wgid & 31;                 // hidden slice 0..31
    const int tid   = threadIdx.x;
    const int wave  = tid >> 6;                  // gate index
    const int lane  = tid & 63;
    const int quad  = lane >> 4, l16 = lane & 15;
    const int j0 = j_sl * 16;
    const int b0 = i_blk * 16;
    const int bt = tid >> 4;                     // batch-local  0..15
    const int ut = tid & 15;                     // unit-local   0..15

    // --- register-resident B fragments (gate `wave`, units j0..j0+16) ---
    bf16x8 bq[16];
    {
        const unsigned short* urow =
            Ut + (size_t)(wave * HID + j0 + l16) * KDIM + quad * 8;
        for (int s = 0; s < 16; ++s)
            bq[s] = *(const bf16x8*)(urow + s * 32);
    }
    // --- per-thread state + init publish (version 1 -> parity 0) ---
    float aown = a0[(size_t)(b0 + bt) * HID + j0 + ut];
    __hip_atomic_store(
        &abq[(size_t)i_blk * BLK_DW + j_sl * 256 + tid],
        (unsigned)f2bf(aown) | (1u << 16),
        __ATOMIC_RELAXED, __HIP_MEMORY_SCOPE_AGENT);

    for (int t = 0; t < T_STEPS; ++t) {
        // --- prefetch xW gate addends (contiguous 2 KB block, dense) ---
        unsigned short xs[4];
        {
            const unsigned short* xp =
                xWp + (((size_t)t * BB + i_blk) * NSL + j_sl) * 1024;
#pragma unroll
            for (int w = 0; w < 4; ++w)
                xs[w] = xp[w * 256 + tid];
        }
        // --- stage a_{t-1}: bulk 8x dwordx4 sc1 load doubles as the poll;
        //     each (wave,chunk) span is exactly one producer slice
        //     (j = 4*chunk + wave), so retries are per-wave and re-load
        //     only the stale 1KB spans. ---
        const unsigned* srcblk =
            abq + (size_t)(t & 1) * PAR_DW + (size_t)i_blk * BLK_DW;
        const u32x4* pc = (const u32x4*)srcblk + tid;
        const unsigned w16 = (unsigned)(t + 1) << 16;
        u32x4 d0, d1, d2, d3, d4, d5, d6, d7;
        asm volatile(
            "global_load_dwordx4 %0, %8, off sc1\n\t"
            "global_load_dwordx4 %1, %9, off sc1\n\t"
            "global_load_dwordx4 %2, %10, off sc1\n\t"
            "global_load_dwordx4 %3, %11, off sc1\n\t"
            "global_load_dwordx4 %4, %12, off sc1\n\t"
            "global_load_dwordx4 %5, %13, off sc1\n\t"
            "global_load_dwordx4 %6, %14, off sc1\n\t"
            "global_load_dwordx4 %7, %15, off sc1\n\t"
            "s_waitcnt vmcnt(0)"
            : "=&v"(d0), "=&v"(d1), "=&v"(d2), "=&v"(d3),
              "=&v"(d4), "=&v"(d5), "=&v"(d6), "=&v"(d7)
            : "v"(pc),        "v"(pc + 256),  "v"(pc + 512),
              "v"(pc + 768),  "v"(pc + 1024), "v"(pc + 1280),
              "v"(pc + 1536), "v"(pc + 1792)
            : "memory");
        // per-span validate + cheap retry (wave-uniform via __all; rare path)
#define FIX(d, off)                                                         \
        while (!__all((int)(min4(d) >= w16))) {                             \
            asm volatile("global_load_dwordx4 %0, %1, off sc1\n\t"          \
                         "s_waitcnt vmcnt(0)"                               \
                         : "=&v"(d) : "v"(pc + (off)) : "memory");          \
        }
        FIX(d0, 0)    FIX(d1, 256)  FIX(d2, 512)  FIX(d3, 768)
        FIX(d4, 1024) FIX(d5, 1280) FIX(d6, 1536) FIX(d7, 1792)
#undef FIX
        // scatter to LDS: strip tags, 8B packed writes
#define SCAT(q, d)                                                          \
        {                                                                   \
            int c = (q) * 256 + tid;                                        \
            unsigned lo = ((d)[0] & 0xffffu) | ((d)[1] << 16);              \
            unsigned hi = ((d)[2] & 0xffffu) | ((d)[3] << 16);              \
            uint2 pk; pk.x = lo; pk.y = hi;                                 \
            *(uint2*)&a_lds[(c >> 2) & 15][(c >> 6) * 16 + (c & 3) * 4] = pk;\
        }
        SCAT(0, d0) SCAT(1, d1) SCAT(2, d2) SCAT(3, d3)
        SCAT(4, d4) SCAT(5, d5) SCAT(6, d6) SCAT(7, d7)
#undef SCAT
        __syncthreads();

        // --- MFMA: M=16 (batch), N=16 (units), K=512; 4 indep chains ---
        f32x4 acc0 = (f32x4)0.0f, acc1 = (f32x4)0.0f;
        f32x4 acc2 = (f32x4)0.0f, acc3 = (f32x4)0.0f;
#pragma unroll
        for (int s = 0; s < 16; s += 4) {
            bf16x8 af0 = *(const bf16x8*)&a_lds[l16][(s + 0) * 32 + quad * 8];
            bf16x8 af1 = *(const bf16x8*)&a_lds[l16][(s + 1) * 32 + quad * 8];
            bf16x8 af2 = *(const bf16x8*)&a_lds[l16][(s + 2) * 32 + quad * 8];
            bf16x8 af3 = *(const bf16x8*)&a_lds[l16][(s + 3) * 32 + quad * 8];
            acc0 = __builtin_amdgcn_mfma_f32_16x16x32_bf16(af0, bq[s + 0], acc0, 0, 0, 0);
            acc1 = __builtin_amdgcn_mfma_f32_16x16x32_bf16(af1, bq[s + 1], acc1, 0, 0, 0);
            acc2 = __builtin_amdgcn_mfma_f32_16x16x32_bf16(af2, bq[s + 2], acc2, 0, 0, 0);
            acc3 = __builtin_amdgcn_mfma_f32_16x16x32_bf16(af3, bq[s + 3], acc3, 0, 0, 0);
        }
#pragma unroll
        for (int r = 0; r < 4; ++r)
            gbuf[wave][quad * 4 + r][l16] =
                (acc0[r] + acc1[r]) + (acc2[r] + acc3[r]);
        __syncthreads();

        // --- gates (thread (bt,ut)); publish FIRST, out-store after ---
        {
            float gu = gbuf[0][bt][ut] + bf2f(xs[0]);
            float gf = gbuf[1][bt][ut] + bf2f(xs[1]);
            float go = gbuf[2][bt][ut] + bf2f(xs[2]);
            float gc = gbuf[3][bt][ut] + bf2f(xs[3]);
            float su = 1.f / (1.f + __expf(-gu));
            float sf = 1.f / (1.f + __expf(-gf));
            float so = 1.f / (1.f + __expf(-go));
            float e2 = __expf(2.f * gc);
            float tc = 1.f - 2.f / (e2 + 1.f);            // tanh(gc)
            float cc = su * tc + sf * aown;                // forget * a_{t-1}
            float ec = __expf(2.f * cc);
            float th = 1.f - 2.f / (ec + 1.f);             // tanh(c)
            float a  = so * th;
            aown = a;
            __hip_atomic_store(
                &abq[(size_t)((t + 1) & 1) * PAR_DW + (size_t)i_blk * BLK_DW +
                     j_sl * 256 + tid],
                (unsigned)f2bf(a) | ((unsigned)(t + 2) << 16),
                __ATOMIC_RELAXED, __HIP_MEMORY_SCOPE_AGENT);
            out[((size_t)t * NB + b0 + bt) * HID + j0 + ut] = a;
        }
        // next iteration's first __syncthreads separates a_lds reuse
    }
}

// ---------------------------------------------------------------------------
extern "C" void kernel_launch(void* const* d_in, const int* in_sizes, int n_in,
                              void* d_out, int out_size, void* d_ws, size_t ws_size,
                              hipStream_t stream) {
    (void)in_sizes; (void)n_in; (void)out_size; (void)ws_size;
    const float* x    = (const float*)d_in[0];   // [T,B,I]
    const float* a0   = (const float*)d_in[1];   // [B,H]
    const float* W    = (const float*)d_in[2];   // [I,4H]
    const float* U    = (const float*)d_in[3];   // [H,4H]
    const float* bias = (const float*)d_in[4];   // [4H]
    float* out = (float*)d_out;

    char* ws = (char*)d_ws;
    unsigned short* xbf  = (unsigned short*)(ws);                 // 33,554,432 B
    unsigned short* Wt   = (unsigned short*)(ws + 33554432);      //  2,097,152 B
    unsigned short* Ut   = (unsigned short*)(ws + 35651584);      //  2,097,152 B
    unsigned short* xWp  = (unsigned short*)(ws + 37748736);      // 134,217,728 B
    unsigned*       abq  = (unsigned*)(ws + 171966464);           //    262,144 B

    cast_x_kernel<<<16384, 256, 0, stream>>>(x, xbf, abq);
    transpose_cast<<<dim3(32, 8), 256, 0, stream>>>(W, Wt);
    transpose_cast<<<dim3(32, 8), 256, 0, stream>>>(U, Ut);
    gemm_xw<<<dim3(256, 16), 256, 0, stream>>>(xbf, Wt, bias, xWp);
    lstm_rec<<<BB * NSL, 256, 0, stream>>>(xWp, Ut, a0, out, abq);
}

// Round 3
// 1491.735 us; speedup vs baseline: 1.3976x; 1.3976x over previous
//
#include <hip/hip_runtime.h>
#include <cstddef>
#include <cstdint>

// ---------------------------------------------------------------------------
// LSTM layer: T=512, B=64, I=512, H=512.
// Phase 1: xW = x @ W + b  (bf16 MFMA GEMM), epilogue writes xWp in
//          per-WG-per-step contiguous layout [t][blk][slice][gate][256].
// Phase 2: persistent recurrence, 128 WGs = 4 batch-blocks x 32 hidden-slices.
//   R8:  tagged-word exchange with coalesced dwordx4 sc1 staging, bulk load
//        doubles as the freshness poll (data+check in one MALL round trip).
//   R11: masked PARALLEL span retry — retry rounds re-issue only the stale
//        (wave,chunk) spans (slice j = 4*chunk + wave), but all in the SAME
//        round with one shared waitcnt, preserving R8's max-over-laggards
//        latency while cutting retry transfer 32KB -> ~2KB.
//        (R10's serial per-span retry loops paid one RTT per stale span,
//        sequentially — regressed; reverted. R9's flag pre-gate also
//        regressed: detect->fetch serialization + 2-line hot-spot.)
//        Plus: xW gate addends prefetched one step ahead (unroll-by-2 A/B
//        buffers) so their HBM miss latency hides under a full step instead
//        of padding the first exchange round's waitcnt.
// ---------------------------------------------------------------------------

#define T_STEPS 512
#define NB      64      // batch
#define HID     512
#define G4      2048    // 4*H
#define KDIM    512
#define BB      4       // batch blocks (16 rows each)
#define NSL     32      // hidden slices (16 units each)
#define BLK_DW  (NSL * 256)          // dwords per (parity,block) region = 8192
#define PAR_DW  (BB * BLK_DW)        // dwords per parity = 32768

typedef short bf16x8 __attribute__((ext_vector_type(8)));
typedef float f32x4  __attribute__((ext_vector_type(4)));
typedef unsigned int u32x4 __attribute__((ext_vector_type(4)));

__device__ __forceinline__ float bf2f(unsigned short s) {
    unsigned u = ((unsigned)s) << 16;
    float f; __builtin_memcpy(&f, &u, 4); return f;
}
__device__ __forceinline__ unsigned short f2bf(float f) {
    unsigned u; __builtin_memcpy(&u, &f, 4);
    u = (u + 0x7FFFu + ((u >> 16) & 1u)) >> 16;
    return (unsigned short)u;
}
__device__ __forceinline__ unsigned min4(u32x4 v) {
    unsigned a = v[0] < v[1] ? v[0] : v[1];
    unsigned b = v[2] < v[3] ? v[2] : v[3];
    return a < b ? a : b;
}

// ---------------- kernel 1: cast x to bf16 + zero both abq parity regions --
__global__ void cast_x_kernel(const float* __restrict__ x,
                              unsigned short* __restrict__ o,
                              unsigned* __restrict__ abq) {
    if (blockIdx.x < 256)   // 256 x 256 = 65536 dwords = 256 KB
        abq[blockIdx.x * 256 + threadIdx.x] = 0u;   // tag 0 = stale
    size_t i = (size_t)blockIdx.x * blockDim.x + threadIdx.x;  // one float4 each
    float4 v = ((const float4*)x)[i];
    ushort4 r;
    r.x = f2bf(v.x); r.y = f2bf(v.y); r.z = f2bf(v.z); r.w = f2bf(v.w);
    ((ushort4*)o)[i] = r;
}

// ---------------- kernel 2: transpose+cast [512][2048] f32 -> [2048][512] bf16
__global__ void transpose_cast(const float* __restrict__ src,
                               unsigned short* __restrict__ dst) {
    __shared__ float tile[64][65];
    const int n0 = blockIdx.x * 64;
    const int k0 = blockIdx.y * 64;
    const int c  = threadIdx.x & 63;
    const int r0 = threadIdx.x >> 6;
    for (int p = 0; p < 16; ++p) {
        int r = p * 4 + r0;
        tile[r][c] = src[(size_t)(k0 + r) * G4 + n0 + c];
    }
    __syncthreads();
    for (int p = 0; p < 16; ++p) {
        int r = p * 4 + r0;
        dst[(size_t)(n0 + r) * KDIM + k0 + c] = f2bf(tile[c][r]);
    }
}

// ---------------- kernel 3: bf16 MFMA GEMM, recurrence-layout epilogue ------
// C layout: [t][blk][slice][gate][bt*16+ut] bf16 (contiguous 2 KB per WG-step)
__global__ __launch_bounds__(256) void gemm_xw(
        const unsigned short* __restrict__ A,
        const unsigned short* __restrict__ Bt,
        const float* __restrict__ bias,
        unsigned short* __restrict__ C) {
    __shared__ unsigned short As[128][56];
    __shared__ unsigned short Bs[128][56];
    const int m0 = blockIdx.x * 128;
    const int n0 = blockIdx.y * 128;
    const int tid = threadIdx.x;
    const int lane = tid & 63, wave = tid >> 6;
    const int quad = lane >> 4, l16 = lane & 15;
    const int wm = (wave >> 1) * 64, wn = (wave & 1) * 64;
    f32x4 acc[4][4];
    for (int i = 0; i < 4; ++i)
        for (int j = 0; j < 4; ++j) acc[i][j] = (f32x4)0.0f;
    const int srow = tid >> 2, scol = (tid & 3) * 8;
    for (int k0 = 0; k0 < KDIM; k0 += 32) {
        __syncthreads();
        for (int p = 0; p < 2; ++p) {
            int row = p * 64 + srow;
            *(uint4*)&As[row][scol] =
                *(const uint4*)&A[(size_t)(m0 + row) * KDIM + k0 + scol];
            *(uint4*)&Bs[row][scol] =
                *(const uint4*)&Bt[(size_t)(n0 + row) * KDIM + k0 + scol];
        }
        __syncthreads();
        bf16x8 af[4], bf[4];
        for (int i = 0; i < 4; ++i)
            af[i] = *(const bf16x8*)&As[wm + i * 16 + l16][quad * 8];
        for (int j = 0; j < 4; ++j)
            bf[j] = *(const bf16x8*)&Bs[wn + j * 16 + l16][quad * 8];
        for (int i = 0; i < 4; ++i)
            for (int j = 0; j < 4; ++j)
                acc[i][j] = __builtin_amdgcn_mfma_f32_16x16x32_bf16(
                    af[i], bf[j], acc[i][j], 0, 0, 0);
    }
    for (int i = 0; i < 4; ++i)
        for (int j = 0; j < 4; ++j) {
            int col = n0 + wn + j * 16 + l16;          // 0..2047
            int g   = col >> 9;                        // gate
            int u   = col & 511;                       // hidden unit
            int js  = u >> 4, ut = u & 15;
            float bv = bias[col];
            for (int r = 0; r < 4; ++r) {
                int row = m0 + wm + i * 16 + quad * 4 + r;   // t*64 + b
                int t = row >> 6, b = row & 63;
                size_t off = ((((size_t)t * BB + (b >> 4)) * NSL + js) * 4 + g)
                                 * 256 + (b & 15) * 16 + ut;
                C[off] = f2bf(acc[i][j][r] + bv);
            }
        }
}

// ---------------- kernel 4: persistent recurrence (tagged, masked retry) ---
// abq dword layout: [parity][block i][slice j][d], d = b_local*16 + u_local.
// Word = bf16(value) | version<<16. Version of a_t is t+1 (a0 -> 1).
__global__ __launch_bounds__(256) void lstm_rec(
        const unsigned short* __restrict__ xWp,  // [t][blk][slice][4][256] bf16
        const unsigned short* __restrict__ Ut,   // [2048][512] bf16
        const float* __restrict__ a0,            // [64][512] f32
        float* __restrict__ out,                 // [T*64][512] f32
        unsigned* __restrict__ abq) {            // 2*4*32*256 dwords = 256 KB
    __shared__ unsigned short a_lds[16][520];    // [batch-local][k-global]
    __shared__ float gbuf[4][16][20];            // [gate][batch-local][unit]
    const int wgid  = blockIdx.x;
    const int i_blk = wgid >> 5;                 // batch block 0..3
    const int j_sl  = wgid & 31;                 // hidden slice 0..31
    const int tid   = threadIdx.x;
    const int wave  = tid >> 6;                  // gate index
    const int lane  = tid & 63;
    const int quad  = lane >> 4, l16 = lane & 15;
    const int j0 = j_sl * 16;
    const int b0 = i_blk * 16;
    const int bt = tid >> 4;                     // batch-local  0..15
    const int ut = tid & 15;                     // unit-local   0..15

    // --- register-resident B fragments (gate `wave`, units j0..j0+16) ---
    bf16x8 bq[16];
    {
        const unsigned short* urow =
            Ut + (size_t)(wave * HID + j0 + l16) * KDIM + quad * 8;
        for (int s = 0; s < 16; ++s)
            bq[s] = *(const bf16x8*)(urow + s * 32);
    }
    // --- per-thread state + init publish (version 1 -> parity 0) ---
    float aown = a0[(size_t)(b0 + bt) * HID + j0 + ut];
    __hip_atomic_store(
        &abq[(size_t)i_blk * BLK_DW + j_sl * 256 + tid],
        (unsigned)f2bf(aown) | (1u << 16),
        __ATOMIC_RELAXED, __HIP_MEMORY_SCOPE_AGENT);

    // --- xW addend prefetch pipeline (A/B register buffers) ---
    unsigned short xsA[4], xsB[4];
    {
        const unsigned short* xp =
            xWp + ((size_t)i_blk * NSL + j_sl) * 1024;   // t = 0
#pragma unroll
        for (int w = 0; w < 4; ++w)
            xsA[w] = xp[w * 256 + tid];
    }

    auto step = [&](int t, unsigned short* xs, unsigned short* xsn) {
        // --- stage a_{t-1}: bulk 8x dwordx4 sc1 load doubles as the poll.
        //     Each (wave,chunk) span is exactly one producer slice
        //     (j = 4*chunk + wave). Retry rounds re-issue ONLY stale spans,
        //     all in the same round (one shared waitcnt) -> max-over-laggards
        //     latency with minimal MALL traffic. ---
        const unsigned* srcblk =
            abq + (size_t)(t & 1) * PAR_DW + (size_t)i_blk * BLK_DW;
        const u32x4* pc = (const u32x4*)srcblk + tid;
        const unsigned w16 = (unsigned)(t + 1) << 16;
        u32x4 d0, d1, d2, d3, d4, d5, d6, d7;
        unsigned ok = 0;   // wave-uniform span-valid bitmask
        do {
            if (!(ok & 1u))
                asm volatile("global_load_dwordx4 %0, %1, off sc1"
                             : "=&v"(d0) : "v"(pc) : "memory");
            if (!(ok & 2u))
                asm volatile("global_load_dwordx4 %0, %1, off sc1"
                             : "=&v"(d1) : "v"(pc + 256) : "memory");
            if (!(ok & 4u))
                asm volatile("global_load_dwordx4 %0, %1, off sc1"
                             : "=&v"(d2) : "v"(pc + 512) : "memory");
            if (!(ok & 8u))
                asm volatile("global_load_dwordx4 %0, %1, off sc1"
                             : "=&v"(d3) : "v"(pc + 768) : "memory");
            if (!(ok & 16u))
                asm volatile("global_load_dwordx4 %0, %1, off sc1"
                             : "=&v"(d4) : "v"(pc + 1024) : "memory");
            if (!(ok & 32u))
                asm volatile("global_load_dwordx4 %0, %1, off sc1"
                             : "=&v"(d5) : "v"(pc + 1280) : "memory");
            if (!(ok & 64u))
                asm volatile("global_load_dwordx4 %0, %1, off sc1"
                             : "=&v"(d6) : "v"(pc + 1536) : "memory");
            if (!(ok & 128u))
                asm volatile("global_load_dwordx4 %0, %1, off sc1"
                             : "=&v"(d7) : "v"(pc + 1792) : "memory");
            asm volatile("s_waitcnt vmcnt(0)" ::: "memory");
            if (!(ok & 1u)   && __all((int)(min4(d0) >= w16))) ok |= 1u;
            if (!(ok & 2u)   && __all((int)(min4(d1) >= w16))) ok |= 2u;
            if (!(ok & 4u)   && __all((int)(min4(d2) >= w16))) ok |= 4u;
            if (!(ok & 8u)   && __all((int)(min4(d3) >= w16))) ok |= 8u;
            if (!(ok & 16u)  && __all((int)(min4(d4) >= w16))) ok |= 16u;
            if (!(ok & 32u)  && __all((int)(min4(d5) >= w16))) ok |= 32u;
            if (!(ok & 64u)  && __all((int)(min4(d6) >= w16))) ok |= 64u;
            if (!(ok & 128u) && __all((int)(min4(d7) >= w16))) ok |= 128u;
        } while (ok != 255u);

        // --- prefetch next step's xW addends (HBM latency hides under the
        //     rest of this step; drained by next step's retry waitcnt) ---
        {
            int tn = (t + 1 < T_STEPS) ? t + 1 : t;
            const unsigned short* xp =
                xWp + (((size_t)tn * BB + i_blk) * NSL + j_sl) * 1024;
#pragma unroll
            for (int w = 0; w < 4; ++w)
                xsn[w] = xp[w * 256 + tid];
        }

        // scatter to LDS: strip tags, 8B packed writes
#define SCAT(q, d)                                                          \
        {                                                                   \
            int c = (q) * 256 + tid;                                        \
            unsigned lo = ((d)[0] & 0xffffu) | ((d)[1] << 16);              \
            unsigned hi = ((d)[2] & 0xffffu) | ((d)[3] << 16);              \
            uint2 pk; pk.x = lo; pk.y = hi;                                 \
            *(uint2*)&a_lds[(c >> 2) & 15][(c >> 6) * 16 + (c & 3) * 4] = pk;\
        }
        SCAT(0, d0) SCAT(1, d1) SCAT(2, d2) SCAT(3, d3)
        SCAT(4, d4) SCAT(5, d5) SCAT(6, d6) SCAT(7, d7)
#undef SCAT
        __syncthreads();

        // --- MFMA: M=16 (batch), N=16 (units), K=512; 4 indep chains ---
        f32x4 acc0 = (f32x4)0.0f, acc1 = (f32x4)0.0f;
        f32x4 acc2 = (f32x4)0.0f, acc3 = (f32x4)0.0f;
#pragma unroll
        for (int s = 0; s < 16; s += 4) {
            bf16x8 af0 = *(const bf16x8*)&a_lds[l16][(s + 0) * 32 + quad * 8];
            bf16x8 af1 = *(const bf16x8*)&a_lds[l16][(s + 1) * 32 + quad * 8];
            bf16x8 af2 = *(const bf16x8*)&a_lds[l16][(s + 2) * 32 + quad * 8];
            bf16x8 af3 = *(const bf16x8*)&a_lds[l16][(s + 3) * 32 + quad * 8];
            acc0 = __builtin_amdgcn_mfma_f32_16x16x32_bf16(af0, bq[s + 0], acc0, 0, 0, 0);
            acc1 = __builtin_amdgcn_mfma_f32_16x16x32_bf16(af1, bq[s + 1], acc1, 0, 0, 0);
            acc2 = __builtin_amdgcn_mfma_f32_16x16x32_bf16(af2, bq[s + 2], acc2, 0, 0, 0);
            acc3 = __builtin_amdgcn_mfma_f32_16x16x32_bf16(af3, bq[s + 3], acc3, 0, 0, 0);
        }
#pragma unroll
        for (int r = 0; r < 4; ++r)
            gbuf[wave][quad * 4 + r][l16] =
                (acc0[r] + acc1[r]) + (acc2[r] + acc3[r]);
        __syncthreads();

        // --- gates (thread (bt,ut)); publish FIRST, out-store after ---
        {
            float gu = gbuf[0][bt][ut] + bf2f(xs[0]);
            float gf = gbuf[1][bt][ut] + bf2f(xs[1]);
            float go = gbuf[2][bt][ut] + bf2f(xs[2]);
            float gc = gbuf[3][bt][ut] + bf2f(xs[3]);
            float su = 1.f / (1.f + __expf(-gu));
            float sf = 1.f / (1.f + __expf(-gf));
            float so = 1.f / (1.f + __expf(-go));
            float e2 = __expf(2.f * gc);
            float tc = 1.f - 2.f / (e2 + 1.f);            // tanh(gc)
            float cc = su * tc + sf * aown;                // forget * a_{t-1}
            float ec = __expf(2.f * cc);
            float th = 1.f - 2.f / (ec + 1.f);             // tanh(c)
            float a  = so * th;
            aown = a;
            __hip_atomic_store(
                &abq[(size_t)((t + 1) & 1) * PAR_DW + (size_t)i_blk * BLK_DW +
                     j_sl * 256 + tid],
                (unsigned)f2bf(a) | ((unsigned)(t + 2) << 16),
                __ATOMIC_RELAXED, __HIP_MEMORY_SCOPE_AGENT);
            out[((size_t)t * NB + b0 + bt) * HID + j0 + ut] = a;
        }
        // the gbuf-phase __syncthreads separates a_lds reuse across steps
    };

    for (int t = 0; t < T_STEPS; t += 2) {
        step(t,     xsA, xsB);
        step(t + 1, xsB, xsA);
    }
}

// ---------------------------------------------------------------------------
extern "C" void kernel_launch(void* const* d_in, const int* in_sizes, int n_in,
                              void* d_out, int out_size, void* d_ws, size_t ws_size,
                              hipStream_t stream) {
    (void)in_sizes; (void)n_in; (void)out_size; (void)ws_size;
    const float* x    = (const float*)d_in[0];   // [T,B,I]
    const float* a0   = (const float*)d_in[1];   // [B,H]
    const float* W    = (const float*)d_in[2];   // [I,4H]
    const float* U    = (const float*)d_in[3];   // [H,4H]
    const float* bias = (const float*)d_in[4];   // [4H]
    float* out = (float*)d_out;

    char* ws = (char*)d_ws;
    unsigned short* xbf  = (unsigned short*)(ws);                 // 33,554,432 B
    unsigned short* Wt   = (unsigned short*)(ws + 33554432);      //  2,097,152 B
    unsigned short* Ut   = (unsigned short*)(ws + 35651584);      //  2,097,152 B
    unsigned short* xWp  = (unsigned short*)(ws + 37748736);      // 134,217,728 B
    unsigned*       abq  = (unsigned*)(ws + 171966464);           //    262,144 B

    cast_x_kernel<<<16384, 256, 0, stream>>>(x, xbf, abq);
    transpose_cast<<<dim3(32, 8), 256, 0, stream>>>(W, Wt);
    transpose_cast<<<dim3(32, 8), 256, 0, stream>>>(U, Ut);
    gemm_xw<<<dim3(256, 16), 256, 0, stream>>>(xbf, Wt, bias, xWp);
    lstm_rec<<<BB * NSL, 256, 0, stream>>>(xWp, Ut, a0, out, abq);
}

// Round 4
// 1452.304 us; speedup vs baseline: 1.4356x; 1.0272x over previous
//
#include <hip/hip_runtime.h>
#include <cstddef>
#include <cstdint>

// ---------------------------------------------------------------------------
// LSTM layer: T=512, B=64, I=512, H=512.
// Phase 1: xW = x @ W + b  (bf16 MFMA GEMM), epilogue writes xWp in
//          per-WG-per-step contiguous layout [t][blk][slice][gate][256].
// Phase 2: persistent recurrence, 128 WGs = 4 batch-blocks x 32 hidden-slices.
//   R8:  tagged-word exchange with coalesced dwordx4 sc1 staging, bulk load
//        doubles as the freshness poll (data+check in one MALL round trip).
//        Full-reload retry — measured best among retry structures (R9 flag
//        pre-gate, R10 serial span retry, R11 masked parallel retry all
//        regressed; R8's ~1-2 rounds/step are latency-, not BW-, limited).
//   R12: keep abq MALL-resident. FETCH/WRITE accounting showed ~400KB/step
//        of HBM reads + ~128KB/step of HBM writes beyond xWp/out = the 256KB
//        abq buffer thrashing out of the Infinity Cache under the xWp/out
//        streams. Fix: nt (non-temporal) loads for xWp, nt stores for out,
//        so streams stop evicting the exchange buffer; exchange rounds run
//        at MALL-hit (~400cy) instead of HBM-miss (~900cy) latency.
//        xW addends also prefetched one step ahead (A/B buffers) so their
//        HBM latency hides under a full step.
// ---------------------------------------------------------------------------

#define T_STEPS 512
#define NB      64      // batch
#define HID     512
#define G4      2048    // 4*H
#define KDIM    512
#define BB      4       // batch blocks (16 rows each)
#define NSL     32      // hidden slices (16 units each)
#define BLK_DW  (NSL * 256)          // dwords per (parity,block) region = 8192
#define PAR_DW  (BB * BLK_DW)        // dwords per parity = 32768

typedef short bf16x8 __attribute__((ext_vector_type(8)));
typedef float f32x4  __attribute__((ext_vector_type(4)));
typedef unsigned int u32x4 __attribute__((ext_vector_type(4)));

__device__ __forceinline__ float bf2f(unsigned short s) {
    unsigned u = ((unsigned)s) << 16;
    float f; __builtin_memcpy(&f, &u, 4); return f;
}
__device__ __forceinline__ unsigned short f2bf(float f) {
    unsigned u; __builtin_memcpy(&u, &f, 4);
    u = (u + 0x7FFFu + ((u >> 16) & 1u)) >> 16;
    return (unsigned short)u;
}
__device__ __forceinline__ unsigned min4(u32x4 v) {
    unsigned a = v[0] < v[1] ? v[0] : v[1];
    unsigned b = v[2] < v[3] ? v[2] : v[3];
    return a < b ? a : b;
}

// ---------------- kernel 1: cast x to bf16 + zero both abq parity regions --
__global__ void cast_x_kernel(const float* __restrict__ x,
                              unsigned short* __restrict__ o,
                              unsigned* __restrict__ abq) {
    if (blockIdx.x < 256)   // 256 x 256 = 65536 dwords = 256 KB
        abq[blockIdx.x * 256 + threadIdx.x] = 0u;   // tag 0 = stale
    size_t i = (size_t)blockIdx.x * blockDim.x + threadIdx.x;  // one float4 each
    float4 v = ((const float4*)x)[i];
    ushort4 r;
    r.x = f2bf(v.x); r.y = f2bf(v.y); r.z = f2bf(v.z); r.w = f2bf(v.w);
    ((ushort4*)o)[i] = r;
}

// ---------------- kernel 2: transpose+cast [512][2048] f32 -> [2048][512] bf16
__global__ void transpose_cast(const float* __restrict__ src,
                               unsigned short* __restrict__ dst) {
    __shared__ float tile[64][65];
    const int n0 = blockIdx.x * 64;
    const int k0 = blockIdx.y * 64;
    const int c  = threadIdx.x & 63;
    const int r0 = threadIdx.x >> 6;
    for (int p = 0; p < 16; ++p) {
        int r = p * 4 + r0;
        tile[r][c] = src[(size_t)(k0 + r) * G4 + n0 + c];
    }
    __syncthreads();
    for (int p = 0; p < 16; ++p) {
        int r = p * 4 + r0;
        dst[(size_t)(n0 + r) * KDIM + k0 + c] = f2bf(tile[c][r]);
    }
}

// ---------------- kernel 3: bf16 MFMA GEMM, recurrence-layout epilogue ------
// C layout: [t][blk][slice][gate][bt*16+ut] bf16 (contiguous 2 KB per WG-step)
__global__ __launch_bounds__(256) void gemm_xw(
        const unsigned short* __restrict__ A,
        const unsigned short* __restrict__ Bt,
        const float* __restrict__ bias,
        unsigned short* __restrict__ C) {
    __shared__ unsigned short As[128][56];
    __shared__ unsigned short Bs[128][56];
    const int m0 = blockIdx.x * 128;
    const int n0 = blockIdx.y * 128;
    const int tid = threadIdx.x;
    const int lane = tid & 63, wave = tid >> 6;
    const int quad = lane >> 4, l16 = lane & 15;
    const int wm = (wave >> 1) * 64, wn = (wave & 1) * 64;
    f32x4 acc[4][4];
    for (int i = 0; i < 4; ++i)
        for (int j = 0; j < 4; ++j) acc[i][j] = (f32x4)0.0f;
    const int srow = tid >> 2, scol = (tid & 3) * 8;
    for (int k0 = 0; k0 < KDIM; k0 += 32) {
        __syncthreads();
        for (int p = 0; p < 2; ++p) {
            int row = p * 64 + srow;
            *(uint4*)&As[row][scol] =
                *(const uint4*)&A[(size_t)(m0 + row) * KDIM + k0 + scol];
            *(uint4*)&Bs[row][scol] =
                *(const uint4*)&Bt[(size_t)(n0 + row) * KDIM + k0 + scol];
        }
        __syncthreads();
        bf16x8 af[4], bf[4];
        for (int i = 0; i < 4; ++i)
            af[i] = *(const bf16x8*)&As[wm + i * 16 + l16][quad * 8];
        for (int j = 0; j < 4; ++j)
            bf[j] = *(const bf16x8*)&Bs[wn + j * 16 + l16][quad * 8];
        for (int i = 0; i < 4; ++i)
            for (int j = 0; j < 4; ++j)
                acc[i][j] = __builtin_amdgcn_mfma_f32_16x16x32_bf16(
                    af[i], bf[j], acc[i][j], 0, 0, 0);
    }
    for (int i = 0; i < 4; ++i)
        for (int j = 0; j < 4; ++j) {
            int col = n0 + wn + j * 16 + l16;          // 0..2047
            int g   = col >> 9;                        // gate
            int u   = col & 511;                       // hidden unit
            int js  = u >> 4, ut = u & 15;
            float bv = bias[col];
            for (int r = 0; r < 4; ++r) {
                int row = m0 + wm + i * 16 + quad * 4 + r;   // t*64 + b
                int t = row >> 6, b = row & 63;
                size_t off = ((((size_t)t * BB + (b >> 4)) * NSL + js) * 4 + g)
                                 * 256 + (b & 15) * 16 + ut;
                C[off] = f2bf(acc[i][j][r] + bv);
            }
        }
}

// ---------------- kernel 4: persistent recurrence (tagged dwordx4 sc1) -----
// abq dword layout: [parity][block i][slice j][d], d = b_local*16 + u_local.
// Word = bf16(value) | version<<16. Version of a_t is t+1 (a0 -> 1).
__global__ __launch_bounds__(256) void lstm_rec(
        const unsigned short* __restrict__ xWp,  // [t][blk][slice][4][256] bf16
        const unsigned short* __restrict__ Ut,   // [2048][512] bf16
        const float* __restrict__ a0,            // [64][512] f32
        float* __restrict__ out,                 // [T*64][512] f32
        unsigned* __restrict__ abq) {            // 2*4*32*256 dwords = 256 KB
    __shared__ unsigned short a_lds[16][520];    // [batch-local][k-global]
    __shared__ float gbuf[4][16][20];            // [gate][batch-local][unit]
    const int wgid  = blockIdx.x;
    const int i_blk = wgid >> 5;                 // batch block 0..3
    const int j_sl  = wgid & 31;                 // hidden slice 0..31
    const int tid   = threadIdx.x;
    const int wave  = tid >> 6;                  // gate index
    const int lane  = tid & 63;
    const int quad  = lane >> 4, l16 = lane & 15;
    const int j0 = j_sl * 16;
    const int b0 = i_blk * 16;
    const int bt = tid >> 4;                     // batch-local  0..15
    const int ut = tid & 15;                     // unit-local   0..15

    // --- register-resident B fragments (gate `wave`, units j0..j0+16) ---
    bf16x8 bq[16];
    {
        const unsigned short* urow =
            Ut + (size_t)(wave * HID + j0 + l16) * KDIM + quad * 8;
        for (int s = 0; s < 16; ++s)
            bq[s] = *(const bf16x8*)(urow + s * 32);
    }
    // --- per-thread state + init publish (version 1 -> parity 0) ---
    float aown = a0[(size_t)(b0 + bt) * HID + j0 + ut];
    __hip_atomic_store(
        &abq[(size_t)i_blk * BLK_DW + j_sl * 256 + tid],
        (unsigned)f2bf(aown) | (1u << 16),
        __ATOMIC_RELAXED, __HIP_MEMORY_SCOPE_AGENT);

    // --- xW addend prefetch pipeline (A/B register buffers, nt loads) ---
    unsigned short xsA[4], xsB[4];
    {
        const unsigned short* xp =
            xWp + ((size_t)i_blk * NSL + j_sl) * 1024;   // t = 0
#pragma unroll
        for (int w = 0; w < 4; ++w)
            xsA[w] = __builtin_nontemporal_load(&xp[w * 256 + tid]);
    }

    auto step = [&](int t, unsigned short* xs, unsigned short* xsn) {
        // --- stage a_{t-1}: 8 tagged 16B chunks, coalesced dwordx4 sc1,
        //     uniform full-reload retry (R8 structure; measured best) ---
        const unsigned* srcblk =
            abq + (size_t)(t & 1) * PAR_DW + (size_t)i_blk * BLK_DW;
        const u32x4* pc = (const u32x4*)srcblk + tid;
        const unsigned w16 = (unsigned)(t + 1) << 16;
        u32x4 d0, d1, d2, d3, d4, d5, d6, d7;
        bool okf;
        do {
            asm volatile(
                "global_load_dwordx4 %0, %8, off sc1\n\t"
                "global_load_dwordx4 %1, %9, off sc1\n\t"
                "global_load_dwordx4 %2, %10, off sc1\n\t"
                "global_load_dwordx4 %3, %11, off sc1\n\t"
                "global_load_dwordx4 %4, %12, off sc1\n\t"
                "global_load_dwordx4 %5, %13, off sc1\n\t"
                "global_load_dwordx4 %6, %14, off sc1\n\t"
                "global_load_dwordx4 %7, %15, off sc1\n\t"
                "s_waitcnt vmcnt(0)"
                : "=&v"(d0), "=&v"(d1), "=&v"(d2), "=&v"(d3),
                  "=&v"(d4), "=&v"(d5), "=&v"(d6), "=&v"(d7)
                : "v"(pc),        "v"(pc + 256),  "v"(pc + 512),
                  "v"(pc + 768),  "v"(pc + 1024), "v"(pc + 1280),
                  "v"(pc + 1536), "v"(pc + 1792)
                : "memory");
            unsigned m01 = min4(d0) < min4(d1) ? min4(d0) : min4(d1);
            unsigned m23 = min4(d2) < min4(d3) ? min4(d2) : min4(d3);
            unsigned m45 = min4(d4) < min4(d5) ? min4(d4) : min4(d5);
            unsigned m67 = min4(d6) < min4(d7) ? min4(d6) : min4(d7);
            unsigned ma = m01 < m23 ? m01 : m23;
            unsigned mb = m45 < m67 ? m45 : m67;
            okf = ((ma < mb ? ma : mb) >= w16);
        } while (!okf);

        // --- prefetch next step's xW addends (nt: don't evict abq from
        //     MALL; HBM latency hides under the rest of this step) ---
        {
            int tn = (t + 1 < T_STEPS) ? t + 1 : t;
            const unsigned short* xp =
                xWp + (((size_t)tn * BB + i_blk) * NSL + j_sl) * 1024;
#pragma unroll
            for (int w = 0; w < 4; ++w)
                xsn[w] = __builtin_nontemporal_load(&xp[w * 256 + tid]);
        }

        // scatter to LDS: strip tags, 8B packed writes
#define SCAT(q, d)                                                          \
        {                                                                   \
            int c = (q) * 256 + tid;                                        \
            unsigned lo = ((d)[0] & 0xffffu) | ((d)[1] << 16);              \
            unsigned hi = ((d)[2] & 0xffffu) | ((d)[3] << 16);              \
            uint2 pk; pk.x = lo; pk.y = hi;                                 \
            *(uint2*)&a_lds[(c >> 2) & 15][(c >> 6) * 16 + (c & 3) * 4] = pk;\
        }
        SCAT(0, d0) SCAT(1, d1) SCAT(2, d2) SCAT(3, d3)
        SCAT(4, d4) SCAT(5, d5) SCAT(6, d6) SCAT(7, d7)
#undef SCAT
        __syncthreads();

        // --- MFMA: M=16 (batch), N=16 (units), K=512; 4 indep chains ---
        f32x4 acc0 = (f32x4)0.0f, acc1 = (f32x4)0.0f;
        f32x4 acc2 = (f32x4)0.0f, acc3 = (f32x4)0.0f;
#pragma unroll
        for (int s = 0; s < 16; s += 4) {
            bf16x8 af0 = *(const bf16x8*)&a_lds[l16][(s + 0) * 32 + quad * 8];
            bf16x8 af1 = *(const bf16x8*)&a_lds[l16][(s + 1) * 32 + quad * 8];
            bf16x8 af2 = *(const bf16x8*)&a_lds[l16][(s + 2) * 32 + quad * 8];
            bf16x8 af3 = *(const bf16x8*)&a_lds[l16][(s + 3) * 32 + quad * 8];
            acc0 = __builtin_amdgcn_mfma_f32_16x16x32_bf16(af0, bq[s + 0], acc0, 0, 0, 0);
            acc1 = __builtin_amdgcn_mfma_f32_16x16x32_bf16(af1, bq[s + 1], acc1, 0, 0, 0);
            acc2 = __builtin_amdgcn_mfma_f32_16x16x32_bf16(af2, bq[s + 2], acc2, 0, 0, 0);
            acc3 = __builtin_amdgcn_mfma_f32_16x16x32_bf16(af3, bq[s + 3], acc3, 0, 0, 0);
        }
#pragma unroll
        for (int r = 0; r < 4; ++r)
            gbuf[wave][quad * 4 + r][l16] =
                (acc0[r] + acc1[r]) + (acc2[r] + acc3[r]);
        __syncthreads();

        // --- gates (thread (bt,ut)); publish FIRST, out-store after ---
        {
            float gu = gbuf[0][bt][ut] + bf2f(xs[0]);
            float gf = gbuf[1][bt][ut] + bf2f(xs[1]);
            float go = gbuf[2][bt][ut] + bf2f(xs[2]);
            float gc = gbuf[3][bt][ut] + bf2f(xs[3]);
            float su = 1.f / (1.f + __expf(-gu));
            float sf = 1.f / (1.f + __expf(-gf));
            float so = 1.f / (1.f + __expf(-go));
            float e2 = __expf(2.f * gc);
            float tc = 1.f - 2.f / (e2 + 1.f);            // tanh(gc)
            float cc = su * tc + sf * aown;                // forget * a_{t-1}
            float ec = __expf(2.f * cc);
            float th = 1.f - 2.f / (ec + 1.f);             // tanh(c)
            float a  = so * th;
            aown = a;
            __hip_atomic_store(
                &abq[(size_t)((t + 1) & 1) * PAR_DW + (size_t)i_blk * BLK_DW +
                     j_sl * 256 + tid],
                (unsigned)f2bf(a) | ((unsigned)(t + 2) << 16),
                __ATOMIC_RELAXED, __HIP_MEMORY_SCOPE_AGENT);
            __builtin_nontemporal_store(
                a, &out[((size_t)t * NB + b0 + bt) * HID + j0 + ut]);
        }
        // the gbuf-phase __syncthreads separates a_lds reuse across steps
    };

    for (int t = 0; t < T_STEPS; t += 2) {
        step(t,     xsA, xsB);
        step(t + 1, xsB, xsA);
    }
}

// ---------------------------------------------------------------------------
extern "C" void kernel_launch(void* const* d_in, const int* in_sizes, int n_in,
                              void* d_out, int out_size, void* d_ws, size_t ws_size,
                              hipStream_t stream) {
    (void)in_sizes; (void)n_in; (void)out_size; (void)ws_size;
    const float* x    = (const float*)d_in[0];   // [T,B,I]
    const float* a0   = (const float*)d_in[1];   // [B,H]
    const float* W    = (const float*)d_in[2];   // [I,4H]
    const float* U    = (const float*)d_in[3];   // [H,4H]
    const float* bias = (const float*)d_in[4];   // [4H]
    float* out = (float*)d_out;

    char* ws = (char*)d_ws;
    unsigned short* xbf  = (unsigned short*)(ws);                 // 33,554,432 B
    unsigned short* Wt   = (unsigned short*)(ws + 33554432);      //  2,097,152 B
    unsigned short* Ut   = (unsigned short*)(ws + 35651584);      //  2,097,152 B
    unsigned short* xWp  = (unsigned short*)(ws + 37748736);      // 134,217,728 B
    unsigned*       abq  = (unsigned*)(ws + 171966464);           //    262,144 B

    cast_x_kernel<<<16384, 256, 0, stream>>>(x, xbf, abq);
    transpose_cast<<<dim3(32, 8), 256, 0, stream>>>(W, Wt);
    transpose_cast<<<dim3(32, 8), 256, 0, stream>>>(U, Ut);
    gemm_xw<<<dim3(256, 16), 256, 0, stream>>>(xbf, Wt, bias, xWp);
    lstm_rec<<<BB * NSL, 256, 0, stream>>>(xWp, Ut, a0, out, abq);
}

// Round 5
// 1333.528 us; speedup vs baseline: 1.5634x; 1.0891x over previous
//
#include <hip/hip_runtime.h>
#include <cstddef>
#include <cstdint>

// ---------------------------------------------------------------------------
// LSTM layer: T=512, B=64, I=512, H=512.
// Phase 1: xW = x @ W + b  (bf16 MFMA GEMM), epilogue writes xWp in
//          per-WG-per-step contiguous layout [t][blk8][slice16][gate][256].
// Phase 2: persistent recurrence, 128 WGs = 8 batch-blocks x 16 hidden-slices.
//   R13: XCD-local exchange. Recurrence couples only WGs sharing a batch
//        block; with 8 blocks and i_blk = blockIdx & 7, each 16-WG group is
//        one blockIdx residue class mod 8 -> one XCD under round-robin
//        dispatch -> exchange via the SHARED per-XCD L2 (sc0 loads, plain
//        stores, ~180cy) instead of agent-scope MALL RTT (~500cy).
//        Correctness does NOT depend on the mapping:
//         - dual-publish: tagged word stored twice (workgroup-scope -> L2,
//           then agent-scope -> MALL); same value, any cache state is fine.
//         - sticky escape: if a step needs >32 retry rounds (stale-L2
//           starvation), the thread permanently flips its loads to sc1,
//           which always see the agent copy. Worst case = R8 behavior.
//        Retry structure stays R8 (bulk tagged load doubles as the poll;
//        R9/R10/R11 variants all measured worse).
// ---------------------------------------------------------------------------

#define T_STEPS 512
#define NB      64      // batch
#define HID     512
#define G4      2048    // 4*H
#define KDIM    512
#define BB      8       // batch blocks (8 rows each)
#define NSL     16      // hidden slices (32 units each)
#define BLK_DW  (NSL * 256)          // dwords per (parity,block) region = 4096
#define PAR_DW  (BB * BLK_DW)        // dwords per parity = 32768

typedef short bf16x8 __attribute__((ext_vector_type(8)));
typedef float f32x4  __attribute__((ext_vector_type(4)));
typedef unsigned int u32x4 __attribute__((ext_vector_type(4)));

__device__ __forceinline__ float bf2f(unsigned short s) {
    unsigned u = ((unsigned)s) << 16;
    float f; __builtin_memcpy(&f, &u, 4); return f;
}
__device__ __forceinline__ unsigned short f2bf(float f) {
    unsigned u; __builtin_memcpy(&u, &f, 4);
    u = (u + 0x7FFFu + ((u >> 16) & 1u)) >> 16;
    return (unsigned short)u;
}
__device__ __forceinline__ unsigned min4(u32x4 v) {
    unsigned a = v[0] < v[1] ? v[0] : v[1];
    unsigned b = v[2] < v[3] ? v[2] : v[3];
    return a < b ? a : b;
}

// ---------------- kernel 1: cast x to bf16 + zero both abq parity regions --
__global__ void cast_x_kernel(const float* __restrict__ x,
                              unsigned short* __restrict__ o,
                              unsigned* __restrict__ abq) {
    if (blockIdx.x < 256)   // 256 x 256 = 65536 dwords = 256 KB
        abq[blockIdx.x * 256 + threadIdx.x] = 0u;   // tag 0 = stale
    size_t i = (size_t)blockIdx.x * blockDim.x + threadIdx.x;  // one float4 each
    float4 v = ((const float4*)x)[i];
    ushort4 r;
    r.x = f2bf(v.x); r.y = f2bf(v.y); r.z = f2bf(v.z); r.w = f2bf(v.w);
    ((ushort4*)o)[i] = r;
}

// ---------------- kernel 2: transpose+cast [512][2048] f32 -> [2048][512] bf16
__global__ void transpose_cast(const float* __restrict__ src,
                               unsigned short* __restrict__ dst) {
    __shared__ float tile[64][65];
    const int n0 = blockIdx.x * 64;
    const int k0 = blockIdx.y * 64;
    const int c  = threadIdx.x & 63;
    const int r0 = threadIdx.x >> 6;
    for (int p = 0; p < 16; ++p) {
        int r = p * 4 + r0;
        tile[r][c] = src[(size_t)(k0 + r) * G4 + n0 + c];
    }
    __syncthreads();
    for (int p = 0; p < 16; ++p) {
        int r = p * 4 + r0;
        dst[(size_t)(n0 + r) * KDIM + k0 + c] = f2bf(tile[c][r]);
    }
}

// ---------------- kernel 3: bf16 MFMA GEMM, recurrence-layout epilogue ------
// C layout: [t][blk8][slice16][gate][bt*32+ut] bf16 (2 KB per WG-step)
__global__ __launch_bounds__(256) void gemm_xw(
        const unsigned short* __restrict__ A,
        const unsigned short* __restrict__ Bt,
        const float* __restrict__ bias,
        unsigned short* __restrict__ C) {
    __shared__ unsigned short As[128][56];
    __shared__ unsigned short Bs[128][56];
    const int m0 = blockIdx.x * 128;
    const int n0 = blockIdx.y * 128;
    const int tid = threadIdx.x;
    const int lane = tid & 63, wave = tid >> 6;
    const int quad = lane >> 4, l16 = lane & 15;
    const int wm = (wave >> 1) * 64, wn = (wave & 1) * 64;
    f32x4 acc[4][4];
    for (int i = 0; i < 4; ++i)
        for (int j = 0; j < 4; ++j) acc[i][j] = (f32x4)0.0f;
    const int srow = tid >> 2, scol = (tid & 3) * 8;
    for (int k0 = 0; k0 < KDIM; k0 += 32) {
        __syncthreads();
        for (int p = 0; p < 2; ++p) {
            int row = p * 64 + srow;
            *(uint4*)&As[row][scol] =
                *(const uint4*)&A[(size_t)(m0 + row) * KDIM + k0 + scol];
            *(uint4*)&Bs[row][scol] =
                *(const uint4*)&Bt[(size_t)(n0 + row) * KDIM + k0 + scol];
        }
        __syncthreads();
        bf16x8 af[4], bf[4];
        for (int i = 0; i < 4; ++i)
            af[i] = *(const bf16x8*)&As[wm + i * 16 + l16][quad * 8];
        for (int j = 0; j < 4; ++j)
            bf[j] = *(const bf16x8*)&Bs[wn + j * 16 + l16][quad * 8];
        for (int i = 0; i < 4; ++i)
            for (int j = 0; j < 4; ++j)
                acc[i][j] = __builtin_amdgcn_mfma_f32_16x16x32_bf16(
                    af[i], bf[j], acc[i][j], 0, 0, 0);
    }
    for (int i = 0; i < 4; ++i)
        for (int j = 0; j < 4; ++j) {
            int col = n0 + wn + j * 16 + l16;          // 0..2047
            int g   = col >> 9;                        // gate
            int u   = col & 511;                       // hidden unit
            int js  = u >> 5, utl = u & 31;            // slice, unit-local
            float bv = bias[col];
            for (int r = 0; r < 4; ++r) {
                int row = m0 + wm + i * 16 + quad * 4 + r;   // t*64 + b
                int t = row >> 6, b = row & 63;
                size_t off = ((((size_t)t * BB + (b >> 3)) * NSL + js) * 4 + g)
                                 * 256 + (b & 7) * 32 + utl;
                C[off] = f2bf(acc[i][j][r] + bv);
            }
        }
}

// ---------------- kernel 4: persistent recurrence (XCD-local exchange) -----
// abq dword layout: [parity][block i8][slice j16][d], d = b_local*32 + u_local.
// Word = bf16(value) | version<<16. Version of a_t is t+1 (a0 -> 1).
__global__ __launch_bounds__(256, 1) void lstm_rec(
        const unsigned short* __restrict__ xWp,  // [t][blk][slice][4][256] bf16
        const unsigned short* __restrict__ Ut,   // [2048][512] bf16
        const float* __restrict__ a0,            // [64][512] f32
        float* __restrict__ out,                 // [T*64][512] f32
        unsigned* __restrict__ abq) {            // 2*PAR_DW dwords = 256 KB
    __shared__ unsigned short a_lds[16][520];    // [batch-local][k-global]
    __shared__ float gbuf[4][8][36];             // [gate][batch-local][unit]
    const int wgid  = blockIdx.x;
    const int i_blk = wgid & 7;                  // batch block 0..7 = XCD id
    const int j_sl  = wgid >> 3;                 // hidden slice 0..15
    const int tid   = threadIdx.x;
    const int wave  = tid >> 6;                  // gate index
    const int lane  = tid & 63;
    const int quad  = lane >> 4, l16 = lane & 15;
    const int j0 = j_sl * 32;
    const int b0 = i_blk * 8;
    const int bt = tid >> 5;                     // batch-local  0..7
    const int ut = tid & 31;                     // unit-local   0..31

    // zero MFMA A rows 8..15 once (M=16 tile, only 8 batch rows valid)
    for (int i = tid; i < 2080; i += 256)
        ((unsigned*)&a_lds[8][0])[i] = 0u;

    // --- register-resident B fragments: gate `wave`, 32 units (2 N-tiles) ---
    bf16x8 bq[2][16];
#pragma unroll
    for (int n = 0; n < 2; ++n) {
        const unsigned short* urow =
            Ut + (size_t)(wave * HID + j0 + n * 16 + l16) * KDIM + quad * 8;
#pragma unroll
        for (int s = 0; s < 16; ++s)
            bq[n][s] = *(const bf16x8*)(urow + s * 32);
    }

    // --- per-thread state + init dual-publish (version 1 -> parity 0) ---
    float aown = a0[(size_t)(b0 + bt) * HID + j0 + ut];
    {
        unsigned* pp = &abq[(size_t)i_blk * BLK_DW + j_sl * 256 + tid];
        unsigned pv = (unsigned)f2bf(aown) | (1u << 16);
        __hip_atomic_store(pp, pv, __ATOMIC_RELAXED, __HIP_MEMORY_SCOPE_WORKGROUP);
        __hip_atomic_store(pp, pv, __ATOMIC_RELAXED, __HIP_MEMORY_SCOPE_AGENT);
    }

    // --- xW addend prefetch pipeline (A/B register buffers) ---
    unsigned short xsA[4], xsB[4];
    {
        const unsigned short* xp =
            xWp + ((size_t)i_blk * NSL + j_sl) * 1024;   // t = 0
#pragma unroll
        for (int w = 0; w < 4; ++w)
            xsA[w] = xp[w * 256 + tid];
    }

    bool fast = true;    // sticky: sc0 (L2) loads until starvation detected

#define LOADS(FLAG)                                                         \
    asm volatile(                                                           \
        "global_load_dwordx4 %0, %4, off " FLAG "\n\t"                      \
        "global_load_dwordx4 %1, %5, off " FLAG "\n\t"                      \
        "global_load_dwordx4 %2, %6, off " FLAG "\n\t"                      \
        "global_load_dwordx4 %3, %7, off " FLAG "\n\t"                      \
        "s_waitcnt vmcnt(0)"                                                \
        : "=&v"(d0), "=&v"(d1), "=&v"(d2), "=&v"(d3)                        \
        : "v"(pc), "v"(pc + 256), "v"(pc + 512), "v"(pc + 768)              \
        : "memory")

    auto step = [&](int t, unsigned short* xs, unsigned short* xsn) {
        // --- stage a_{t-1}: 4 tagged 16B chunks; bulk load doubles as poll.
        //     fast: sc0 (bypass L1, hit shared XCD L2). slow: sc1 (MALL). ---
        const unsigned* srcblk =
            abq + (size_t)(t & 1) * PAR_DW + (size_t)i_blk * BLK_DW;
        const u32x4* pc = (const u32x4*)srcblk + tid;
        const unsigned w16 = (unsigned)(t + 1) << 16;
        u32x4 d0, d1, d2, d3;
        bool okf;
        int tries = 0;
        do {
            if (__builtin_expect(fast, 1)) { LOADS("sc0"); }
            else                           { LOADS("sc1"); }
            unsigned m01 = min4(d0) < min4(d1) ? min4(d0) : min4(d1);
            unsigned m23 = min4(d2) < min4(d3) ? min4(d2) : min4(d3);
            okf = ((m01 < m23 ? m01 : m23) >= w16);
            if (!okf && ++tries > 32) fast = false;   // starving on stale L2
        } while (!okf);

        // --- prefetch next step's xW addends (hidden under rest of step) ---
        {
            int tn = (t + 1 < T_STEPS) ? t + 1 : t;
            const unsigned short* xp =
                xWp + (((size_t)tn * BB + i_blk) * NSL + j_sl) * 1024;
#pragma unroll
            for (int w = 0; w < 4; ++w)
                xsn[w] = xp[w * 256 + tid];
        }

        // scatter to LDS: strip tags, 8B packed writes
        // dword d = j*256 + b*32 + u  ->  a_lds[b][j*32 + u]
#define SCAT(q, d)                                                          \
        {                                                                   \
            int dd = ((q) << 10) + tid * 4;                                 \
            int bb = (dd >> 5) & 7;                                         \
            int kg = ((dd >> 8) << 5) | (dd & 31);                          \
            unsigned lo = ((d)[0] & 0xffffu) | ((d)[1] << 16);              \
            unsigned hi = ((d)[2] & 0xffffu) | ((d)[3] << 16);              \
            uint2 pk; pk.x = lo; pk.y = hi;                                 \
            *(uint2*)&a_lds[bb][kg] = pk;                                   \
        }
        SCAT(0, d0) SCAT(1, d1) SCAT(2, d2) SCAT(3, d3)
#undef SCAT
        __syncthreads();

        // --- MFMA: M=16 (8 batch rows valid), N=32 (2 tiles), K=512 ---
        f32x4 acc0a = (f32x4)0.0f, acc0b = (f32x4)0.0f;
        f32x4 acc1a = (f32x4)0.0f, acc1b = (f32x4)0.0f;
#pragma unroll
        for (int s = 0; s < 16; s += 2) {
            bf16x8 af0 = *(const bf16x8*)&a_lds[l16][(s + 0) * 32 + quad * 8];
            bf16x8 af1 = *(const bf16x8*)&a_lds[l16][(s + 1) * 32 + quad * 8];
            acc0a = __builtin_amdgcn_mfma_f32_16x16x32_bf16(af0, bq[0][s + 0], acc0a, 0, 0, 0);
            acc1a = __builtin_amdgcn_mfma_f32_16x16x32_bf16(af0, bq[1][s + 0], acc1a, 0, 0, 0);
            acc0b = __builtin_amdgcn_mfma_f32_16x16x32_bf16(af1, bq[0][s + 1], acc0b, 0, 0, 0);
            acc1b = __builtin_amdgcn_mfma_f32_16x16x32_bf16(af1, bq[1][s + 1], acc1b, 0, 0, 0);
        }
        if (quad < 2) {
#pragma unroll
            for (int r = 0; r < 4; ++r) {
                gbuf[wave][quad * 4 + r][l16]      = acc0a[r] + acc0b[r];
                gbuf[wave][quad * 4 + r][16 + l16] = acc1a[r] + acc1b[r];
            }
        }
        __syncthreads();

        // --- gates (thread (bt,ut)); dual-publish FIRST, out-store after ---
        {
            float gu = gbuf[0][bt][ut] + bf2f(xs[0]);
            float gf = gbuf[1][bt][ut] + bf2f(xs[1]);
            float go = gbuf[2][bt][ut] + bf2f(xs[2]);
            float gc = gbuf[3][bt][ut] + bf2f(xs[3]);
            float su = 1.f / (1.f + __expf(-gu));
            float sf = 1.f / (1.f + __expf(-gf));
            float so = 1.f / (1.f + __expf(-go));
            float e2 = __expf(2.f * gc);
            float tc = 1.f - 2.f / (e2 + 1.f);            // tanh(gc)
            float cc = su * tc + sf * aown;                // forget * a_{t-1}
            float ec = __expf(2.f * cc);
            float th = 1.f - 2.f / (ec + 1.f);             // tanh(c)
            float a  = so * th;
            aown = a;
            unsigned* pp = &abq[(size_t)((t + 1) & 1) * PAR_DW +
                                (size_t)i_blk * BLK_DW + j_sl * 256 + tid];
            unsigned pv = (unsigned)f2bf(a) | ((unsigned)(t + 2) << 16);
            // workgroup-scope first (shared-L2 copy), agent-scope last
            // (MALL copy; last store is never dead-store-eliminated)
            __hip_atomic_store(pp, pv, __ATOMIC_RELAXED, __HIP_MEMORY_SCOPE_WORKGROUP);
            __hip_atomic_store(pp, pv, __ATOMIC_RELAXED, __HIP_MEMORY_SCOPE_AGENT);
            out[((size_t)t * NB + b0 + bt) * HID + j0 + ut] = a;
        }
        // the gbuf-phase __syncthreads separates a_lds reuse across steps
    };

    for (int t = 0; t < T_STEPS; t += 2) {
        step(t,     xsA, xsB);
        step(t + 1, xsB, xsA);
    }
#undef LOADS
}

// ---------------------------------------------------------------------------
extern "C" void kernel_launch(void* const* d_in, const int* in_sizes, int n_in,
                              void* d_out, int out_size, void* d_ws, size_t ws_size,
                              hipStream_t stream) {
    (void)in_sizes; (void)n_in; (void)out_size; (void)ws_size;
    const float* x    = (const float*)d_in[0];   // [T,B,I]
    const float* a0   = (const float*)d_in[1];   // [B,H]
    const float* W    = (const float*)d_in[2];   // [I,4H]
    const float* U    = (const float*)d_in[3];   // [H,4H]
    const float* bias = (const float*)d_in[4];   // [4H]
    float* out = (float*)d_out;

    char* ws = (char*)d_ws;
    unsigned short* xbf  = (unsigned short*)(ws);                 // 33,554,432 B
    unsigned short* Wt   = (unsigned short*)(ws + 33554432);      //  2,097,152 B
    unsigned short* Ut   = (unsigned short*)(ws + 35651584);      //  2,097,152 B
    unsigned short* xWp  = (unsigned short*)(ws + 37748736);      // 134,217,728 B
    unsigned*       abq  = (unsigned*)(ws + 171966464);           //    262,144 B

    cast_x_kernel<<<16384, 256, 0, stream>>>(x, xbf, abq);
    transpose_cast<<<dim3(32, 8), 256, 0, stream>>>(W, Wt);
    transpose_cast<<<dim3(32, 8), 256, 0, stream>>>(U, Ut);
    gemm_xw<<<dim3(256, 16), 256, 0, stream>>>(xbf, Wt, bias, xWp);
    lstm_rec<<<BB * NSL, 256, 0, stream>>>(xWp, Ut, a0, out, abq);
}